// Round 1
// baseline (1363.457 us; speedup 1.0000x reference)
//
#include <hip/hip_runtime.h>
#include <math.h>

// ---------------------------------------------------------------------------
// GCN 4-layer forward on MI355X. Round 0: correct fp32 baseline.
// Pipeline: degree count -> rsqrt -> scan -> CSR scatter (sorted by dst)
//           agg(X) -> GEMM1(+b,relu) -> GEMM2 -> agg(+b2,relu)
//           -> GEMM3 -> agg(+b3,relu) -> GEMM4 -> agg(+b4) -> log_softmax
// ---------------------------------------------------------------------------

__global__ __launch_bounds__(256) void count_kernel(const int* __restrict__ dst,
                                                    int* __restrict__ counts, int E) {
    int e = blockIdx.x * 256 + threadIdx.x;
    if (e < E) atomicAdd(&counts[dst[e]], 1);
}

__global__ __launch_bounds__(256) void rsqrt_kernel(const int* __restrict__ counts,
                                                    float* __restrict__ rsq, int N) {
    int n = blockIdx.x * 256 + threadIdx.x;
    if (n < N) rsq[n] = rsqrtf((float)counts[n] + 1.0f);
}

// single-block exclusive scan over N counts -> offs[0..N]
__global__ __launch_bounds__(1024) void scan_kernel(const int* __restrict__ counts,
                                                    int* __restrict__ offs, int N) {
    __shared__ int sums[1024];
    int tid = threadIdx.x;
    int chunk = (N + 1023) / 1024;
    int start = tid * chunk;
    int end = start + chunk; if (end > N) end = N;
    int s = 0;
    for (int i = start; i < end && i >= 0; i++) s += counts[i];
    sums[tid] = s;
    __syncthreads();
    // Hillis-Steele inclusive scan
    for (int off = 1; off < 1024; off <<= 1) {
        int v = (tid >= off) ? sums[tid - off] : 0;
        __syncthreads();
        sums[tid] += v;
        __syncthreads();
    }
    int base = (tid == 0) ? 0 : sums[tid - 1];
    for (int i = start; i < end && i >= 0; i++) {
        offs[i] = base;
        base += counts[i];
    }
    if (tid == 1023) offs[N] = sums[1023];
}

__global__ __launch_bounds__(256) void scatter_kernel(const int* __restrict__ src,
                                                      const int* __restrict__ dst,
                                                      const int* __restrict__ offs,
                                                      int* __restrict__ cursor,
                                                      const float* __restrict__ rsq,
                                                      int* __restrict__ ssrc,
                                                      float* __restrict__ sw, int E) {
    int e = blockIdx.x * 256 + threadIdx.x;
    if (e < E) {
        int d = dst[e];
        int s = src[e];
        int pos = offs[d] + atomicAdd(&cursor[d], 1);
        ssrc[pos] = s;
        sw[pos] = rsq[s] * rsq[d];
    }
}

// ---------------------------------------------------------------------------
// Gather-based aggregation: one wave per node, lane handles float4 of features.
// out[n] = sum_e w_e * G[src_e] + (rsq[n]^2) * G[n]  (+bias) (+relu)
// ---------------------------------------------------------------------------
template <int F, bool BIAS, bool RELU>
__global__ __launch_bounds__(256) void agg_kernel(const float* __restrict__ G,
                                                  const int* __restrict__ offs,
                                                  const int* __restrict__ ssrc,
                                                  const float* __restrict__ sw,
                                                  const float* __restrict__ rsq,
                                                  const float* __restrict__ bias,
                                                  float* __restrict__ out, int N) {
    constexpr int LANES = F / 4;   // active lanes per wave
    int lane = threadIdx.x & 63;
    int node = blockIdx.x * 4 + (threadIdx.x >> 6);
    if (node >= N) return;
    bool active = lane < LANES;

    float sn = rsq[node];
    sn *= sn;
    float4 acc = make_float4(0.f, 0.f, 0.f, 0.f);
    if (active) {
        float4 g = reinterpret_cast<const float4*>(G + (size_t)node * F)[lane];
        acc.x = g.x * sn; acc.y = g.y * sn; acc.z = g.z * sn; acc.w = g.w * sn;
    }
    int e0 = offs[node], e1 = offs[node + 1];
    for (int e = e0; e < e1; e++) {
        int s = ssrc[e];
        float wgt = sw[e];
        if (active) {
            float4 g = reinterpret_cast<const float4*>(G + (size_t)s * F)[lane];
            acc.x = fmaf(wgt, g.x, acc.x);
            acc.y = fmaf(wgt, g.y, acc.y);
            acc.z = fmaf(wgt, g.z, acc.z);
            acc.w = fmaf(wgt, g.w, acc.w);
        }
    }
    if (active) {
        if (BIAS) {
            float4 b = reinterpret_cast<const float4*>(bias)[lane];
            acc.x += b.x; acc.y += b.y; acc.z += b.z; acc.w += b.w;
        }
        if (RELU) {
            acc.x = fmaxf(acc.x, 0.f); acc.y = fmaxf(acc.y, 0.f);
            acc.z = fmaxf(acc.z, 0.f); acc.w = fmaxf(acc.w, 0.f);
        }
        reinterpret_cast<float4*>(out + (size_t)node * F)[lane] = acc;
    }
}

// ---------------------------------------------------------------------------
// fp32 tiled SGEMM: C[M x Nc] = A[M x K] @ B[K x Nc] (+bias) (+relu)
// 64x64 block tile, BK=16, 256 threads, 4x4 per thread.
// ---------------------------------------------------------------------------
template <bool BIAS, bool RELU>
__global__ __launch_bounds__(256) void sgemm(const float* __restrict__ A,
                                             const float* __restrict__ B,
                                             const float* __restrict__ bias,
                                             float* __restrict__ C,
                                             int M, int K, int Nc) {
    __shared__ float As[16][68];
    __shared__ float Bs[16][68];
    int tid = threadIdx.x;
    int tx = tid & 15;       // 0..15 -> col group
    int ty = tid >> 4;       // 0..15 -> row group
    int rowBase = blockIdx.y * 64;
    int colBase = blockIdx.x * 64;

    int aRow = tid >> 2;            // 0..63
    int aK   = (tid & 3) * 4;       // 0,4,8,12
    int bK   = tid >> 4;            // 0..15
    int bCol = (tid & 15) * 4;      // 0..60

    float acc[4][4] = {};

    for (int k0 = 0; k0 < K; k0 += 16) {
        float4 av = make_float4(0.f, 0.f, 0.f, 0.f);
        int gr = rowBase + aRow;
        if (gr < M)
            av = *reinterpret_cast<const float4*>(A + (size_t)gr * K + k0 + aK);
        As[aK + 0][aRow] = av.x;
        As[aK + 1][aRow] = av.y;
        As[aK + 2][aRow] = av.z;
        As[aK + 3][aRow] = av.w;

        float4 bv = make_float4(0.f, 0.f, 0.f, 0.f);
        int gc = colBase + bCol;
        const float* brow = B + (size_t)(k0 + bK) * Nc;
        if (gc + 3 < Nc) {
            bv = *reinterpret_cast<const float4*>(brow + gc);
        } else {
            float t[4] = {0.f, 0.f, 0.f, 0.f};
            #pragma unroll
            for (int j = 0; j < 4; j++)
                if (gc + j < Nc) t[j] = brow[gc + j];
            bv = make_float4(t[0], t[1], t[2], t[3]);
        }
        Bs[bK][bCol + 0] = bv.x;
        Bs[bK][bCol + 1] = bv.y;
        Bs[bK][bCol + 2] = bv.z;
        Bs[bK][bCol + 3] = bv.w;

        __syncthreads();
        #pragma unroll
        for (int kk = 0; kk < 16; kk++) {
            float4 a = *reinterpret_cast<const float4*>(&As[kk][ty * 4]);
            float4 b = *reinterpret_cast<const float4*>(&Bs[kk][tx * 4]);
            acc[0][0] = fmaf(a.x, b.x, acc[0][0]);
            acc[0][1] = fmaf(a.x, b.y, acc[0][1]);
            acc[0][2] = fmaf(a.x, b.z, acc[0][2]);
            acc[0][3] = fmaf(a.x, b.w, acc[0][3]);
            acc[1][0] = fmaf(a.y, b.x, acc[1][0]);
            acc[1][1] = fmaf(a.y, b.y, acc[1][1]);
            acc[1][2] = fmaf(a.y, b.z, acc[1][2]);
            acc[1][3] = fmaf(a.y, b.w, acc[1][3]);
            acc[2][0] = fmaf(a.z, b.x, acc[2][0]);
            acc[2][1] = fmaf(a.z, b.y, acc[2][1]);
            acc[2][2] = fmaf(a.z, b.z, acc[2][2]);
            acc[2][3] = fmaf(a.z, b.w, acc[2][3]);
            acc[3][0] = fmaf(a.w, b.x, acc[3][0]);
            acc[3][1] = fmaf(a.w, b.y, acc[3][1]);
            acc[3][2] = fmaf(a.w, b.z, acc[3][2]);
            acc[3][3] = fmaf(a.w, b.w, acc[3][3]);
        }
        __syncthreads();
    }

    #pragma unroll
    for (int r = 0; r < 4; r++) {
        int row = rowBase + ty * 4 + r;
        if (row >= M) continue;
        #pragma unroll
        for (int c = 0; c < 4; c++) {
            int col = colBase + tx * 4 + c;
            if (col >= Nc) continue;
            float v = acc[r][c];
            if (BIAS) v += bias[col];
            if (RELU) v = fmaxf(v, 0.f);
            C[(size_t)row * Nc + col] = v;
        }
    }
}

// ---------------------------------------------------------------------------
// log_softmax over 40 classes: one wave per node.
// ---------------------------------------------------------------------------
__global__ __launch_bounds__(256) void logsoftmax_kernel(const float* __restrict__ in,
                                                         float* __restrict__ out, int N) {
    int lane = threadIdx.x & 63;
    int node = blockIdx.x * 4 + (threadIdx.x >> 6);
    if (node >= N) return;
    float v = (lane < 40) ? in[(size_t)node * 40 + lane] : -INFINITY;
    float m = v;
    #pragma unroll
    for (int o = 32; o >= 1; o >>= 1) m = fmaxf(m, __shfl_xor(m, o, 64));
    float ex = (lane < 40) ? expf(v - m) : 0.0f;
    float s = ex;
    #pragma unroll
    for (int o = 32; o >= 1; o >>= 1) s += __shfl_xor(s, o, 64);
    if (lane < 40) out[(size_t)node * 40 + lane] = v - m - logf(s);
}

// ---------------------------------------------------------------------------

extern "C" void kernel_launch(void* const* d_in, const int* in_sizes, int n_in,
                              void* d_out, int out_size, void* d_ws, size_t ws_size,
                              hipStream_t stream) {
    const float* x  = (const float*)d_in[0];
    const int*   ei = (const int*)d_in[1];
    const float* W1 = (const float*)d_in[2];
    const float* b1 = (const float*)d_in[3];
    const float* W2 = (const float*)d_in[4];
    const float* b2 = (const float*)d_in[5];
    const float* W3 = (const float*)d_in[6];
    const float* b3 = (const float*)d_in[7];
    const float* W4 = (const float*)d_in[8];
    const float* b4 = (const float*)d_in[9];

    const int FIN = 128, HID = 256, C = 40;
    const int N = in_sizes[0] / FIN;
    const int E = in_sizes[1] / 2;
    const int* src = ei;
    const int* dst = ei + E;

    char* w = (char*)d_ws;
    auto alloc = [&](size_t bytes) {
        char* p = w;
        w += (bytes + 255) & ~(size_t)255;
        return p;
    };
    int*   counts = (int*)alloc((size_t)N * 4);
    int*   cursor = (int*)alloc((size_t)N * 4);
    int*   offs   = (int*)alloc((size_t)(N + 1) * 4);
    float* rsq    = (float*)alloc((size_t)N * 4);
    int*   ssrc   = (int*)alloc((size_t)E * 4);
    float* sw     = (float*)alloc((size_t)E * 4);
    float* buf0   = (float*)alloc((size_t)N * HID * 4);
    float* buf1   = (float*)alloc((size_t)N * HID * 4);

    hipMemsetAsync(counts, 0, (size_t)N * 4, stream);
    hipMemsetAsync(cursor, 0, (size_t)N * 4, stream);

    count_kernel<<<(E + 255) / 256, 256, 0, stream>>>(dst, counts, E);
    rsqrt_kernel<<<(N + 255) / 256, 256, 0, stream>>>(counts, rsq, N);
    scan_kernel<<<1, 1024, 0, stream>>>(counts, offs, N);
    scatter_kernel<<<(E + 255) / 256, 256, 0, stream>>>(src, dst, offs, cursor, rsq,
                                                        ssrc, sw, E);

    int aggGrid = (N + 3) / 4;
    dim3 gHID((HID + 63) / 64, (N + 63) / 64);
    dim3 gC((C + 63) / 64, (N + 63) / 64);

    // Layer 1: aggregate X first (128 feats), then GEMM with bias+relu.
    agg_kernel<128, false, false><<<aggGrid, 256, 0, stream>>>(x, offs, ssrc, sw, rsq,
                                                               nullptr, buf1, N);
    sgemm<true, true><<<gHID, 256, 0, stream>>>(buf1, W1, b1, buf0, N, FIN, HID);

    // Layer 2: GEMM -> aggregate(+b2, relu)
    sgemm<false, false><<<gHID, 256, 0, stream>>>(buf0, W2, nullptr, buf1, N, HID, HID);
    agg_kernel<256, true, true><<<aggGrid, 256, 0, stream>>>(buf1, offs, ssrc, sw, rsq,
                                                             b2, buf0, N);

    // Layer 3: GEMM -> aggregate(+b3, relu)
    sgemm<false, false><<<gHID, 256, 0, stream>>>(buf0, W3, nullptr, buf1, N, HID, HID);
    agg_kernel<256, true, true><<<aggGrid, 256, 0, stream>>>(buf1, offs, ssrc, sw, rsq,
                                                             b3, buf0, N);

    // Layer 4: GEMM (Nc=40) -> aggregate(+b4) -> log_softmax
    sgemm<false, false><<<gC, 256, 0, stream>>>(buf0, W4, nullptr, buf1, N, HID, C);
    agg_kernel<40, true, false><<<aggGrid, 256, 0, stream>>>(buf1, offs, ssrc, sw, rsq,
                                                             b4, buf0, N);
    logsoftmax_kernel<<<aggGrid, 256, 0, stream>>>(buf0, (float*)d_out, N);
}

// Round 2
// 920.662 us; speedup vs baseline: 1.4810x; 1.4810x over previous
//
#include <hip/hip_runtime.h>
#include <math.h>

// ---------------------------------------------------------------------------
// GCN 4-layer forward, round 2: bf16 MFMA GEMMs + bf16 gather aggregation.
// fp32 accumulation everywhere; CSR build unchanged from round 1.
// ---------------------------------------------------------------------------

typedef __bf16 bf16x8v __attribute__((ext_vector_type(8)));
typedef float f32x4 __attribute__((ext_vector_type(4)));

__device__ __forceinline__ unsigned short f2bf(float f) {
    union { float f; unsigned u; } v; v.f = f;
    unsigned r = (v.u + 0x7FFFu + ((v.u >> 16) & 1u)) >> 16;
    return (unsigned short)r;
}
__device__ __forceinline__ float bflo(unsigned u) {
    union { unsigned u; float f; } v; v.u = u << 16; return v.f;
}
__device__ __forceinline__ float bfhi(unsigned u) {
    union { unsigned u; float f; } v; v.u = u & 0xFFFF0000u; return v.f;
}

// ------------------------- CSR build ---------------------------------------

__global__ __launch_bounds__(256) void count_kernel(const int* __restrict__ dst,
                                                    int* __restrict__ counts, int E) {
    int e = blockIdx.x * 256 + threadIdx.x;
    if (e < E) atomicAdd(&counts[dst[e]], 1);
}

__global__ __launch_bounds__(256) void rsqrt_kernel(const int* __restrict__ counts,
                                                    float* __restrict__ rsq, int N) {
    int n = blockIdx.x * 256 + threadIdx.x;
    if (n < N) rsq[n] = rsqrtf((float)counts[n] + 1.0f);
}

__global__ __launch_bounds__(1024) void scan_kernel(const int* __restrict__ counts,
                                                    int* __restrict__ offs, int N) {
    __shared__ int sums[1024];
    int tid = threadIdx.x;
    int chunk = (N + 1023) / 1024;
    int start = tid * chunk;
    int end = start + chunk; if (end > N) end = N;
    int s = 0;
    for (int i = start; i < end && i >= 0; i++) s += counts[i];
    sums[tid] = s;
    __syncthreads();
    for (int off = 1; off < 1024; off <<= 1) {
        int v = (tid >= off) ? sums[tid - off] : 0;
        __syncthreads();
        sums[tid] += v;
        __syncthreads();
    }
    int base = (tid == 0) ? 0 : sums[tid - 1];
    for (int i = start; i < end && i >= 0; i++) {
        offs[i] = base;
        base += counts[i];
    }
    if (tid == 1023) offs[N] = sums[1023];
}

__global__ __launch_bounds__(256) void scatter_kernel(const int* __restrict__ src,
                                                      const int* __restrict__ dst,
                                                      const int* __restrict__ offs,
                                                      int* __restrict__ cursor,
                                                      const float* __restrict__ rsq,
                                                      int* __restrict__ ssrc,
                                                      float* __restrict__ sw, int E) {
    int e = blockIdx.x * 256 + threadIdx.x;
    if (e < E) {
        int d = dst[e];
        int s = src[e];
        int pos = offs[d] + atomicAdd(&cursor[d], 1);
        ssrc[pos] = s;
        sw[pos] = rsq[s] * rsq[d];
    }
}

// ------------------------- dtype conversions -------------------------------

__global__ __launch_bounds__(256) void cvt_f2bf_kernel(const float* __restrict__ in,
                                                       unsigned short* __restrict__ out,
                                                       int n4) {
    int i = blockIdx.x * 256 + threadIdx.x;
    if (i < n4) {
        float4 v = reinterpret_cast<const float4*>(in)[i];
        ushort4 o;
        o.x = f2bf(v.x); o.y = f2bf(v.y); o.z = f2bf(v.z); o.w = f2bf(v.w);
        reinterpret_cast<ushort4*>(out)[i] = o;
    }
}

// W [K][Nc] fp32 -> Wt [Nc][K] bf16
__global__ __launch_bounds__(256) void wtrans_kernel(const float* __restrict__ W,
                                                     unsigned short* __restrict__ Wt,
                                                     int K, int Nc) {
    int i = blockIdx.x * 256 + threadIdx.x;
    if (i < K * Nc) {
        int k = i / Nc, n = i - k * Nc;
        Wt[n * K + k] = f2bf(W[i]);
    }
}

// ------------------------- bf16 gather aggregation -------------------------
// out[n] = sum_e w_e * G[src_e] + (1/deg_n) * G[n]  (+bias) (+relu)
// One wave per node; lane handles DW dwords (2 bf16 each). ACT lanes active.
template <int F, int DW, int ACT, bool BIAS, bool RELU, bool OUTF32>
__global__ __launch_bounds__(256) void agg_bf16_kernel(
        const unsigned short* __restrict__ G, const int* __restrict__ offs,
        const int* __restrict__ ssrc, const float* __restrict__ sw,
        const float* __restrict__ rsq, const float* __restrict__ bias,
        void* __restrict__ out, int N) {
    int lane = threadIdx.x & 63;
    int node = blockIdx.x * 4 + (threadIdx.x >> 6);
    if (node >= N) return;
    bool active = lane < ACT;
    const unsigned* Gu = (const unsigned*)G;
    const int rowU = F / 2;             // dwords per row
    int col = lane * DW;                // dword index within row

    float acc[2 * DW];
    #pragma unroll
    for (int i = 0; i < 2 * DW; i++) acc[i] = 0.f;

    float sn = rsq[node];
    sn *= sn;
    if (active) {
        #pragma unroll
        for (int i = 0; i < DW; i++) {
            unsigned g = Gu[(size_t)node * rowU + col + i];
            acc[2 * i]     = fmaf(sn, bflo(g), acc[2 * i]);
            acc[2 * i + 1] = fmaf(sn, bfhi(g), acc[2 * i + 1]);
        }
    }
    int e = offs[node], e1 = offs[node + 1];
    for (; e + 1 < e1; e += 2) {
        int s0 = ssrc[e], s1 = ssrc[e + 1];
        float w0 = sw[e], w1 = sw[e + 1];
        if (active) {
            unsigned g0[DW], g1[DW];
            #pragma unroll
            for (int i = 0; i < DW; i++) g0[i] = Gu[(size_t)s0 * rowU + col + i];
            #pragma unroll
            for (int i = 0; i < DW; i++) g1[i] = Gu[(size_t)s1 * rowU + col + i];
            #pragma unroll
            for (int i = 0; i < DW; i++) {
                acc[2 * i]     = fmaf(w0, bflo(g0[i]), acc[2 * i]);
                acc[2 * i + 1] = fmaf(w0, bfhi(g0[i]), acc[2 * i + 1]);
                acc[2 * i]     = fmaf(w1, bflo(g1[i]), acc[2 * i]);
                acc[2 * i + 1] = fmaf(w1, bfhi(g1[i]), acc[2 * i + 1]);
            }
        }
    }
    if (e < e1 && active) {
        int s0 = ssrc[e];
        float w0 = sw[e];
        #pragma unroll
        for (int i = 0; i < DW; i++) {
            unsigned g = Gu[(size_t)s0 * rowU + col + i];
            acc[2 * i]     = fmaf(w0, bflo(g), acc[2 * i]);
            acc[2 * i + 1] = fmaf(w0, bfhi(g), acc[2 * i + 1]);
        }
    }
    if (active) {
        #pragma unroll
        for (int i = 0; i < DW; i++) {
            float lo = acc[2 * i], hi = acc[2 * i + 1];
            int f0 = 2 * (col + i);
            if (BIAS) { lo += bias[f0]; hi += bias[f0 + 1]; }
            if (RELU) { lo = fmaxf(lo, 0.f); hi = fmaxf(hi, 0.f); }
            if (OUTF32) {
                float* o = (float*)out + (size_t)node * F + f0;
                o[0] = lo; o[1] = hi;
            } else {
                unsigned p = (unsigned)f2bf(lo) | ((unsigned)f2bf(hi) << 16);
                ((unsigned*)out)[(size_t)node * rowU + col + i] = p;
            }
        }
    }
}

// ------------------------- bf16 MFMA GEMM ----------------------------------
// C[M][Nc] = A[M][K] @ Bt[Nc][K]^T  (+bias) (+relu), fp32 accum, out bf16/fp32.
// 128x128 tile, BK=64, 256 threads = 4 waves in 2x2, 4x4 MFMA tiles per wave.
template <bool BIAS, bool RELU, bool OUTBF16>
__global__ __launch_bounds__(256) void gemm_bf16(
        const unsigned short* __restrict__ A,   // [M][K] bf16
        const unsigned short* __restrict__ Bt,  // [Nc][K] bf16
        const float* __restrict__ bias,
        void* __restrict__ Cout,
        int M, int K, int Nc) {
    __shared__ __align__(16) unsigned short As[128 * 72];  // +8 pad
    __shared__ __align__(16) unsigned short Bs[128 * 72];
    int tid = threadIdx.x;
    int lane = tid & 63;
    int wid = tid >> 6;
    int rowBase = blockIdx.y * 128;
    int colBase = blockIdx.x * 128;
    int waveM = (wid & 1) * 64;
    int waveN = (wid >> 1) * 64;

    f32x4 acc[4][4] = {};

    int lrow = lane & 15;
    int kgrp = (lane >> 4) * 8;

    for (int k0 = 0; k0 < K; k0 += 64) {
        #pragma unroll
        for (int i = 0; i < 4; i++) {
            int c = tid + 256 * i;          // 0..1023
            int row = c >> 3;               // 0..127
            int kp = (c & 7) * 8;           // 0..56
            int4 av = make_int4(0, 0, 0, 0);
            int gr = rowBase + row;
            if (gr < M)
                av = *reinterpret_cast<const int4*>(A + (size_t)gr * K + k0 + kp);
            *reinterpret_cast<int4*>(&As[row * 72 + kp]) = av;
            int4 bv = make_int4(0, 0, 0, 0);
            int gc = colBase + row;
            if (gc < Nc)
                bv = *reinterpret_cast<const int4*>(Bt + (size_t)gc * K + k0 + kp);
            *reinterpret_cast<int4*>(&Bs[row * 72 + kp]) = bv;
        }
        __syncthreads();
        #pragma unroll
        for (int kk = 0; kk < 64; kk += 32) {
            bf16x8v af[4], bf[4];
            #pragma unroll
            for (int t = 0; t < 4; t++) {
                af[t] = *reinterpret_cast<const bf16x8v*>(
                    &As[(waveM + t * 16 + lrow) * 72 + kk + kgrp]);
                bf[t] = *reinterpret_cast<const bf16x8v*>(
                    &Bs[(waveN + t * 16 + lrow) * 72 + kk + kgrp]);
            }
            #pragma unroll
            for (int mt = 0; mt < 4; mt++)
                #pragma unroll
                for (int nt = 0; nt < 4; nt++)
                    acc[mt][nt] = __builtin_amdgcn_mfma_f32_16x16x32_bf16(
                        af[mt], bf[nt], acc[mt][nt], 0, 0, 0);
        }
        __syncthreads();
    }

    // epilogue: C/D layout col=lane&15, row=(lane>>4)*4+reg
    #pragma unroll
    for (int mt = 0; mt < 4; mt++) {
        #pragma unroll
        for (int r = 0; r < 4; r++) {
            int row = rowBase + waveM + mt * 16 + (lane >> 4) * 4 + r;
            if (row >= M) continue;
            #pragma unroll
            for (int nt = 0; nt < 4; nt++) {
                int col = colBase + waveN + nt * 16 + (lane & 15);
                if (col >= Nc) continue;
                float v = acc[mt][nt][r];
                if (BIAS) v += bias[col];
                if (RELU) v = fmaxf(v, 0.f);
                if (OUTBF16)
                    ((unsigned short*)Cout)[(size_t)row * Nc + col] = f2bf(v);
                else
                    ((float*)Cout)[(size_t)row * Nc + col] = v;
            }
        }
    }
}

// ------------------------- log_softmax -------------------------------------

__global__ __launch_bounds__(256) void logsoftmax_kernel(const float* __restrict__ in,
                                                         float* __restrict__ out, int N) {
    int lane = threadIdx.x & 63;
    int node = blockIdx.x * 4 + (threadIdx.x >> 6);
    if (node >= N) return;
    float v = (lane < 40) ? in[(size_t)node * 40 + lane] : -INFINITY;
    float m = v;
    #pragma unroll
    for (int o = 32; o >= 1; o >>= 1) m = fmaxf(m, __shfl_xor(m, o, 64));
    float ex = (lane < 40) ? expf(v - m) : 0.0f;
    float s = ex;
    #pragma unroll
    for (int o = 32; o >= 1; o >>= 1) s += __shfl_xor(s, o, 64);
    if (lane < 40) out[(size_t)node * 40 + lane] = v - m - logf(s);
}

// ---------------------------------------------------------------------------

extern "C" void kernel_launch(void* const* d_in, const int* in_sizes, int n_in,
                              void* d_out, int out_size, void* d_ws, size_t ws_size,
                              hipStream_t stream) {
    const float* x  = (const float*)d_in[0];
    const int*   ei = (const int*)d_in[1];
    const float* W1 = (const float*)d_in[2];
    const float* b1 = (const float*)d_in[3];
    const float* W2 = (const float*)d_in[4];
    const float* b2 = (const float*)d_in[5];
    const float* W3 = (const float*)d_in[6];
    const float* b3 = (const float*)d_in[7];
    const float* W4 = (const float*)d_in[8];
    const float* b4 = (const float*)d_in[9];

    const int FIN = 128, HID = 256, C = 40;
    const int N = in_sizes[0] / FIN;
    const int E = in_sizes[1] / 2;
    const int* src = ei;
    const int* dst = ei + E;

    char* w = (char*)d_ws;
    auto alloc = [&](size_t bytes) {
        char* p = w;
        w += (bytes + 255) & ~(size_t)255;
        return p;
    };
    int*   counts = (int*)alloc((size_t)N * 4);
    int*   cursor = (int*)alloc((size_t)N * 4);
    int*   offs   = (int*)alloc((size_t)(N + 1) * 4);
    float* rsq    = (float*)alloc((size_t)N * 4);
    int*   ssrc   = (int*)alloc((size_t)E * 4);
    float* sw     = (float*)alloc((size_t)E * 4);
    unsigned short* xb   = (unsigned short*)alloc((size_t)N * FIN * 2);
    unsigned short* aggx = (unsigned short*)alloc((size_t)N * FIN * 2);
    unsigned short* bufA = (unsigned short*)alloc((size_t)N * HID * 2);
    unsigned short* bufB = (unsigned short*)alloc((size_t)N * HID * 2);
    float* logits = (float*)alloc((size_t)N * C * 4);
    unsigned short* Wt1 = (unsigned short*)alloc((size_t)FIN * HID * 2);
    unsigned short* Wt2 = (unsigned short*)alloc((size_t)HID * HID * 2);
    unsigned short* Wt3 = (unsigned short*)alloc((size_t)HID * HID * 2);
    unsigned short* Wt4 = (unsigned short*)alloc((size_t)HID * C * 2);

    hipMemsetAsync(counts, 0, (size_t)N * 4, stream);
    hipMemsetAsync(cursor, 0, (size_t)N * 4, stream);

    // conversions (independent of CSR build)
    cvt_f2bf_kernel<<<(N * FIN / 4 + 255) / 256, 256, 0, stream>>>(x, xb, N * FIN / 4);
    wtrans_kernel<<<(FIN * HID + 255) / 256, 256, 0, stream>>>(W1, Wt1, FIN, HID);
    wtrans_kernel<<<(HID * HID + 255) / 256, 256, 0, stream>>>(W2, Wt2, HID, HID);
    wtrans_kernel<<<(HID * HID + 255) / 256, 256, 0, stream>>>(W3, Wt3, HID, HID);
    wtrans_kernel<<<(HID * C + 255) / 256, 256, 0, stream>>>(W4, Wt4, HID, C);

    count_kernel<<<(E + 255) / 256, 256, 0, stream>>>(dst, counts, E);
    rsqrt_kernel<<<(N + 255) / 256, 256, 0, stream>>>(counts, rsq, N);
    scan_kernel<<<1, 1024, 0, stream>>>(counts, offs, N);
    scatter_kernel<<<(E + 255) / 256, 256, 0, stream>>>(src, dst, offs, cursor, rsq,
                                                        ssrc, sw, E);

    int aggGrid = (N + 3) / 4;
    dim3 gHID((HID + 127) / 128, (N + 127) / 128);
    dim3 gC((C + 127) / 128, (N + 127) / 128);

    // Layer 1: aggregate x (128 feats) then GEMM(+b1, relu)
    agg_bf16_kernel<128, 1, 64, false, false, false>
        <<<aggGrid, 256, 0, stream>>>(xb, offs, ssrc, sw, rsq, nullptr, aggx, N);
    gemm_bf16<true, true, true><<<gHID, 256, 0, stream>>>(aggx, Wt1, b1, bufA,
                                                          N, FIN, HID);
    // Layer 2: GEMM -> agg(+b2, relu)
    gemm_bf16<false, false, true><<<gHID, 256, 0, stream>>>(bufA, Wt2, nullptr, bufB,
                                                            N, HID, HID);
    agg_bf16_kernel<256, 2, 64, true, true, false>
        <<<aggGrid, 256, 0, stream>>>(bufB, offs, ssrc, sw, rsq, b2, bufA, N);
    // Layer 3: GEMM -> agg(+b3, relu)
    gemm_bf16<false, false, true><<<gHID, 256, 0, stream>>>(bufA, Wt3, nullptr, bufB,
                                                            N, HID, HID);
    agg_bf16_kernel<256, 2, 64, true, true, false>
        <<<aggGrid, 256, 0, stream>>>(bufB, offs, ssrc, sw, rsq, b3, bufA, N);
    // Layer 4: GEMM (Nc=40) -> agg(+b4) -> log_softmax
    gemm_bf16<false, false, true><<<gC, 256, 0, stream>>>(bufA, Wt4, nullptr, bufB,
                                                          N, HID, C);
    agg_bf16_kernel<40, 1, 20, true, false, true>
        <<<aggGrid, 256, 0, stream>>>(bufB, offs, ssrc, sw, rsq, b4, logits, N);
    logsoftmax_kernel<<<aggGrid, 256, 0, stream>>>(logits, (float*)d_out, N);
}